// Round 6
// baseline (756.882 us; speedup 1.0000x reference)
//
#include <hip/hip_runtime.h>

#define DD 64
#define NBKT 512
#define CHUNK 8192
#define CAP_B 13312   // bucket capacity in edges (mean 10.7K, ~24 sigma slack)

struct SegCfg {
    int qbase[4];   // first bucket id of segment
    int rpb[4];     // rows per bucket
    float inv[4];   // 1.f / rpb
    int soff[4];    // global row offset of segment
    int rows[4];    // rows in segment
};

// ---------- K1: 512-way multisplit with dense, full-line bucket writes ----------
__global__ void __launch_bounds__(512, 2)
split_kernel(const int* __restrict__ dA, const int* __restrict__ sA, const int* __restrict__ tA,
             const int* __restrict__ dB, const int* __restrict__ sB, const int* __restrict__ tB,
             const int* __restrict__ dC, const int* __restrict__ sC,
             const int* __restrict__ dD, const int* __restrict__ sD,
             int nA, int nB, int nC, int nD,
             SegCfg cfg, int* __restrict__ gcur, unsigned long long* __restrict__ bkt) {
    __shared__ unsigned long long ord[CHUNK];   // 64 KB
    __shared__ int cnt[NBKT];
    __shared__ int sc[NBKT];
    __shared__ int gb[NBKT];
    int t = threadIdx.x;
    int Etot = nA + nB + nC + nD;
    int base = blockIdx.x * CHUNK;
    if (base >= Etot) return;

    cnt[t] = 0;
    __syncthreads();

    unsigned long long val[16];
    int qv[16], rv[16];
#pragma unroll
    for (int k = 0; k < 16; ++k) {
        int i = base + k * 512 + t;
        qv[k] = -1;
        if (i < Etot) {
            int j = i, d, seg, pv;
            if (j < nA)              { seg = 0; d = dA[j]; pv = sA[j] | (tA[j] << 20); }
            else if ((j -= nA) < nB) { seg = 1; d = dB[j]; pv = sB[j] | (tB[j] << 20); }
            else if ((j -= nB) < nC) { seg = 2; d = dC[j]; pv = sC[j]; }
            else { j -= nC;            seg = 3; d = dD[j]; pv = sD[j]; }
            int rpb = cfg.rpb[seg];
            int q = (int)((float)d * cfg.inv[seg]);
            if (d >= (q + 1) * rpb) ++q;
            else if (d < q * rpb) --q;
            int g = d + cfg.soff[seg];
            val[k] = ((unsigned long long)g << 25) | (unsigned)pv;
            qv[k] = q + cfg.qbase[seg];
            rv[k] = atomicAdd(&cnt[qv[k]], 1);
        }
    }
    __syncthreads();

    // exclusive scan of cnt -> sc; per-bucket global cursor -> gb
    {
        int v = cnt[t];
        sc[t] = v;
        __syncthreads();
        for (int off = 1; off < NBKT; off <<= 1) {
            int y = (t >= off) ? sc[t - off] : 0;
            __syncthreads();
            sc[t] += y;
            __syncthreads();
        }
        sc[t] -= v;   // exclusive
        gb[t] = (v > 0) ? atomicAdd(&gcur[t], v) : 0;
    }
    __syncthreads();

#pragma unroll
    for (int k = 0; k < 16; ++k)
        if (qv[k] >= 0) ord[sc[qv[k]] + rv[k]] = val[k];
    __syncthreads();

    // streamout: wave w handles buckets w, w+8, ...; contiguous runs.
    // Hard-clamped to bucket capacity (overflow -> dropped edges, not OOB fault).
    int wv = t >> 6, lane = t & 63;
    for (int q = wv; q < NBKT; q += 8) {
        int len = cnt[q];
        if (!len) continue;
        int room = CAP_B - gb[q];
        if (room <= 0) continue;
        if (len > room) len = room;
        int s0 = sc[q];
        unsigned long long* dst = bkt + (size_t)q * CAP_B + gb[q];
        for (int l = lane; l < len; l += 64) dst[l] = ord[s0 + l];
    }
}

// ---------- K2: fused per-bucket counting sort + gather-reduce ----------
// One block per bucket. LDS histogram -> scan -> payload scatter into LDS stage,
// then 8 waves gather-reduce their rows straight from LDS (no pay/rowptr round
// trip). Embedding row base becomes an SGPR via readlane. weight (8 KB) is read
// from global: L1-resident, same as the round-3 kernel that verified.
// Static LDS kept at 62 KB == the exact footprint that passed in round 3.
__global__ void __launch_bounds__(512, 2)
sort_gather(const unsigned long long* __restrict__ bkt, const int* __restrict__ gcur,
            SegCfg cfg,
            const float* __restrict__ entity_emb, const float* __restrict__ user_emb,
            const float* __restrict__ weight,
            float* __restrict__ out, float* __restrict__ usr_out,
            float* __restrict__ iu, float* __restrict__ ui) {
    __shared__ int cnt[2048];
    __shared__ int part[512];
    __shared__ int stage[CAP_B];     // 52 KB
    int b = blockIdx.x, t = threadIdx.x;

    int seg = 0;
    if (b >= cfg.qbase[3]) seg = 3;
    else if (b >= cfg.qbase[2]) seg = 2;
    else if (b >= cfg.qbase[1]) seg = 1;
    int lb = b - cfg.qbase[seg];
    int row0 = cfg.soff[seg] + lb * cfg.rpb[seg];
    int nr = cfg.rows[seg] - lb * cfg.rpb[seg];
    if (nr > cfg.rpb[seg]) nr = cfg.rpb[seg];
    int n = gcur[b];
    if (n > CAP_B) n = CAP_B;        // overflow guard (matches split clamp)
    const unsigned long long* src = bkt + (size_t)b * CAP_B;

    // block-uniform source table and destination base
    const float* emb = (seg == 0 || seg == 3) ? entity_emb : user_emb;
    float* dbase;
    if (seg == 0)      dbase = out     + (size_t)row0 * DD;
    else if (seg == 1) dbase = usr_out + (size_t)(row0 - cfg.soff[1]) * DD;
    else if (seg == 2) dbase = iu      + (size_t)(row0 - cfg.soff[2]) * DD;
    else               dbase = ui      + (size_t)(row0 - cfg.soff[3]) * DD;

    for (int i = t; i < 2048; i += 512) cnt[i] = 0;
    __syncthreads();
    for (int i = t; i < n; i += 512) {
        int g = (int)(src[i] >> 25);
        atomicAdd(&cnt[g - row0], 1);
    }
    __syncthreads();

    // exclusive scan of cnt[0..2048): 4 elems/thread + scan of partials
    {
        int s = 0;
#pragma unroll
        for (int k = 0; k < 4; ++k) s += cnt[t * 4 + k];
        part[t] = s;
        __syncthreads();
        for (int off = 1; off < 512; off <<= 1) {
            int y = (t >= off) ? part[t - off] : 0;
            __syncthreads();
            part[t] += y;
            __syncthreads();
        }
        int run = part[t] - s;
#pragma unroll
        for (int k = 0; k < 4; ++k) { int c = cnt[t * 4 + k]; cnt[t * 4 + k] = run; run += c; }
    }
    __syncthreads();

    // scatter payloads into LDS stage (cnt consumed as cursors -> cnt[r] = row end)
    for (int i = t; i < n; i += 512) {
        unsigned long long v = src[i];
        int lr = (int)(v >> 25) - row0;
        int pos = atomicAdd(&cnt[lr], 1);
        stage[pos] = (int)(v & 0x1FFFFFF);
    }
    __syncthreads();

    // per-row gather-reduce: wave per row, payload broadcast from LDS
    int wv = t >> 6, lane = t & 63;
    for (int r = wv; r < nr; r += 8) {
        int start = (r == 0) ? 0 : cnt[r - 1];
        int end = cnt[r];
        float acc = 0.f;
        for (int base = start; base < end; base += 64) {
            int m = end - base; if (m > 64) m = 64;
            int pv = (lane < m) ? stage[base + lane] : 0;
            int j = 0;
            for (; j + 4 <= m; j += 4) {
                int p0 = __builtin_amdgcn_readlane(pv, j);
                int p1 = __builtin_amdgcn_readlane(pv, j + 1);
                int p2 = __builtin_amdgcn_readlane(pv, j + 2);
                int p3 = __builtin_amdgcn_readlane(pv, j + 3);
                const float* r0 = emb + (((unsigned)p0 & 0xFFFFFu) << 6);
                const float* r1 = emb + (((unsigned)p1 & 0xFFFFFu) << 6);
                const float* r2 = emb + (((unsigned)p2 & 0xFFFFFu) << 6);
                const float* r3 = emb + (((unsigned)p3 & 0xFFFFFu) << 6);
                float e0 = r0[lane], w0 = weight[(((unsigned)p0 >> 20) << 6) + lane];
                float e1 = r1[lane], w1 = weight[(((unsigned)p1 >> 20) << 6) + lane];
                float e2 = r2[lane], w2 = weight[(((unsigned)p2 >> 20) << 6) + lane];
                float e3 = r3[lane], w3 = weight[(((unsigned)p3 >> 20) << 6) + lane];
                acc += e0 * w0; acc += e1 * w1; acc += e2 * w2; acc += e3 * w3;
            }
            for (; j < m; ++j) {
                int pj = __builtin_amdgcn_readlane(pv, j);
                const float* rj = emb + (((unsigned)pj & 0xFFFFFu) << 6);
                acc += rj[lane] * weight[(((unsigned)pj >> 20) << 6) + lane];
            }
        }
        int deg = end - start;
        dbase[(size_t)r * DD + lane] = acc / (float)(deg > 0 ? deg : 1);
    }
}

// ---------- gated fusion (in-place safe: per-element RAW only) ----------
__global__ void gate_fuse_kernel(const float* a_, const float* b_,
                                 const float* __restrict__ gA, const float* __restrict__ gB,
                                 float* out, int n_rows) {
    __shared__ float GA[DD][DD + 1];
    __shared__ float GB[DD][DD + 1];
    for (int i = threadIdx.x; i < DD * DD; i += blockDim.x) {
        int d = i >> 6, k = i & 63;
        GA[k][d] = gA[i];
        GB[k][d] = gB[i];
    }
    __syncthreads();
    int lane = threadIdx.x & 63;
    int waves_per_blk = blockDim.x >> 6;
    int row0 = blockIdx.x * waves_per_blk + (threadIdx.x >> 6);
    int stride = gridDim.x * waves_per_blk;
    for (int row = row0; row < n_rows; row += stride) {
        float a = a_[(size_t)row * DD + lane];
        float b = b_[(size_t)row * DD + lane];
        float z = 0.f;
#pragma unroll
        for (int k = 0; k < DD; ++k) {
            float ak = __shfl(a, k, 64);
            float bk = __shfl(b, k, 64);
            z += ak * GA[k][lane] + bk * GB[k][lane];
        }
        float g = 1.f / (1.f + expf(-z));
        out[(size_t)row * DD + lane] = g * a + (1.f - g) * b;
    }
}

extern "C" void kernel_launch(void* const* d_in, const int* in_sizes, int n_in,
                              void* d_out, int out_size, void* d_ws, size_t ws_size,
                              hipStream_t stream) {
    const float* entity_emb = (const float*)d_in[0];
    const float* user_emb   = (const float*)d_in[1];
    const float* weight     = (const float*)d_in[2];
    const float* g1         = (const float*)d_in[3];
    const float* g2         = (const float*)d_in[4];
    const float* g3         = (const float*)d_in[5];
    const int* edge_index  = (const int*)d_in[6];
    const int* edge_type   = (const int*)d_in[7];
    const int* uedge_index = (const int*)d_in[8];
    const int* uedge_type  = (const int*)d_in[9];
    const int* mat_row     = (const int*)d_in[10];
    const int* mat_col     = (const int*)d_in[11];

    const int n_entities   = in_sizes[0] / DD;  // 180000
    const int n_user_nodes = in_sizes[1] / DD;  // 150000
    const int nA           = in_sizes[7];       // 1500000
    const int nB           = in_sizes[9];       // 1000000
    const int nM           = in_sizes[10];      // 1500000
    const int n_items      = 50000;
    const int n_users      = 100000;

    const int offB = n_entities;                // 180000
    const int offC = offB + n_user_nodes;       // 330000
    const int offD = offC + n_items;            // 380000
    const int Etot = nA + nB + nM + nM;         // 5.5M

    float* out      = (float*)d_out;
    float* user_out = out + (size_t)n_entities * DD;

    // workspace (~93 MB): bkt + gcur + iu + ui
    unsigned long long* bkt = (unsigned long long*)d_ws;        // 512*13312*8 = 54.5 MB
    int* gcur = (int*)(bkt + (size_t)NBKT * CAP_B);             // 512
    float* iu = (float*)(gcur + 512);                           // 50k*64 f32
    float* ui = iu + (size_t)n_items * DD;                      // 100k*64 f32

    // expectation-balanced bucket layout
    SegCfg cfg;
    {
        int nb[4];
        nb[0] = (int)((long long)nA * NBKT / Etot);
        nb[1] = (int)((long long)nB * NBKT / Etot);
        nb[2] = (int)((long long)nM * NBKT / Etot);
        nb[3] = NBKT - nb[0] - nb[1] - nb[2];
        int rows[4] = {n_entities, n_user_nodes, n_items, n_users};
        int soff[4] = {0, offB, offC, offD};
        int qb = 0;
        for (int s = 0; s < 4; ++s) {
            cfg.qbase[s] = qb;
            cfg.rpb[s]   = (rows[s] + nb[s] - 1) / nb[s];
            cfg.inv[s]   = 1.0f / (float)cfg.rpb[s];
            cfg.soff[s]  = soff[s];
            cfg.rows[s]  = rows[s];
            qb += nb[s];
        }
    }

    hipMemsetAsync(gcur, 0, 512 * sizeof(int), stream);

    int nchunk = (Etot + CHUNK - 1) / CHUNK;    // 672
    split_kernel<<<nchunk, 512, 0, stream>>>(edge_index, edge_index + nA, edge_type,
                                             uedge_index, uedge_index + nB, uedge_type,
                                             mat_col, mat_row,
                                             mat_row, mat_col,
                                             nA, nB, nM, nM, cfg, gcur, bkt);
    sort_gather<<<NBKT, 512, 0, stream>>>(bkt, gcur, cfg,
                                          entity_emb, user_emb, weight,
                                          out, user_out, iu, ui);

    gate_fuse_kernel<<<1024, 256, 0, stream>>>(out, iu, g1, g2, out, n_items);
    gate_fuse_kernel<<<2048, 256, 0, stream>>>(user_out, ui, g3, g2, user_out, n_users);
}

// Round 7
// 668.123 us; speedup vs baseline: 1.1328x; 1.1328x over previous
//
#include <hip/hip_runtime.h>

#define DD 64
#define NBKT 1024
#define CHUNK 8192
#define CAP_B 6656    // bucket capacity in edges (mean 5371, ~17 sigma slack)

struct SegCfg {
    int qbase[4];   // first bucket id of segment
    int rpb[4];     // rows per bucket
    float inv[4];   // 1.f / rpb
    int soff[4];    // global row offset of segment
    int rows[4];    // rows in segment
};

// ---------- K1: 1024-way multisplit with dense, full-lane streamout ----------
// Each block owns one 8192-edge chunk: decode + classify, LDS rank (count/scan),
// reorder into a 64KB LDS buffer with bucket id packed in bits [44,54), then a
// flat full-lane sweep streams ord[] out: contiguous LDS reads, per-element
// global address gb[q] + (i - sc[q]). Runs of ~8 edges (64B) coalesce per wave.
__global__ void __launch_bounds__(512, 2)
split_kernel(const int* __restrict__ dA, const int* __restrict__ sA, const int* __restrict__ tA,
             const int* __restrict__ dB, const int* __restrict__ sB, const int* __restrict__ tB,
             const int* __restrict__ dC, const int* __restrict__ sC,
             const int* __restrict__ dD, const int* __restrict__ sD,
             int nA, int nB, int nC, int nD,
             SegCfg cfg, int* __restrict__ gcur, unsigned long long* __restrict__ bkt) {
    __shared__ unsigned long long ord[CHUNK];   // 64 KB
    __shared__ int cnt[NBKT];                   // 4 KB
    __shared__ int sc[NBKT];                    // 4 KB
    __shared__ int gb[NBKT];                    // 4 KB (scan scratch, then bases)
    int t = threadIdx.x;
    int Etot = nA + nB + nC + nD;
    int base = blockIdx.x * CHUNK;
    if (base >= Etot) return;

    cnt[t] = 0; cnt[t + 512] = 0;
    __syncthreads();

    unsigned long long val[16];
    int qv[16], rv[16];
#pragma unroll
    for (int k = 0; k < 16; ++k) {
        int i = base + k * 512 + t;
        qv[k] = -1;
        if (i < Etot) {
            int j = i, d, seg, pv;
            if (j < nA)              { seg = 0; d = dA[j]; pv = sA[j] | (tA[j] << 20); }
            else if ((j -= nA) < nB) { seg = 1; d = dB[j]; pv = sB[j] | (tB[j] << 20); }
            else if ((j -= nB) < nC) { seg = 2; d = dC[j]; pv = sC[j]; }
            else { j -= nC;            seg = 3; d = dD[j]; pv = sD[j]; }
            int rpb = cfg.rpb[seg];
            int q = (int)((float)d * cfg.inv[seg]);
            if (d >= (q + 1) * rpb) ++q;
            else if (d < q * rpb) --q;
            int g = d + cfg.soff[seg];
            q += cfg.qbase[seg];
            val[k] = ((unsigned long long)q << 44) | ((unsigned long long)g << 25) | (unsigned)pv;
            qv[k] = q;
            rv[k] = atomicAdd(&cnt[q], 1);
        }
    }
    __syncthreads();

    // exclusive scan of cnt[0..1024): 2 elems/thread, gb[] as partial scratch
    int c0 = cnt[2 * t], c1 = cnt[2 * t + 1];
    {
        int s2 = c0 + c1;
        gb[t] = s2;
        __syncthreads();
        for (int off = 1; off < 512; off <<= 1) {
            int x = (t >= off) ? gb[t - off] : 0;
            __syncthreads();
            gb[t] += x;
            __syncthreads();
        }
        int run = gb[t] - s2;
        sc[2 * t] = run;
        sc[2 * t + 1] = run + c0;
    }
    __syncthreads();
    // per-bucket global bases (overwrite gb)
    gb[2 * t]     = c0 ? atomicAdd(&gcur[2 * t], c0) : 0;
    gb[2 * t + 1] = c1 ? atomicAdd(&gcur[2 * t + 1], c1) : 0;
    __syncthreads();

#pragma unroll
    for (int k = 0; k < 16; ++k)
        if (qv[k] >= 0) ord[sc[qv[k]] + rv[k]] = val[k];
    __syncthreads();

    // full-lane dense streamout (capacity-clamped: overflow drops, never faults)
    int tot = sc[NBKT - 1] + cnt[NBKT - 1];
    for (int i = t; i < tot; i += 512) {
        unsigned long long v = ord[i];
        int q = (int)(v >> 44);
        int idx = gb[q] + (i - sc[q]);
        if (idx < CAP_B)
            bkt[(size_t)q * CAP_B + idx] = v & 0xFFFFFFFFFFFULL;
    }
}

// ---------- K2: fused per-bucket counting sort + gather-reduce ----------
// One block per bucket (1024 blocks = 4/CU exactly). LDS = 32 KB -> 4 blocks/CU,
// 32 waves/CU. LDS histogram -> scan -> payload scatter into LDS stage, then 8
// waves gather-reduce rows straight from LDS. Embedding row base goes to SGPR
// via readlane; weight reads from global (L1-resident).
__global__ void __launch_bounds__(512, 2)
sort_gather(const unsigned long long* __restrict__ bkt, const int* __restrict__ gcur,
            SegCfg cfg,
            const float* __restrict__ entity_emb, const float* __restrict__ user_emb,
            const float* __restrict__ weight,
            float* __restrict__ out, float* __restrict__ usr_out,
            float* __restrict__ iu, float* __restrict__ ui) {
    __shared__ int cnt[1024];        // 4 KB (rows/bucket <= 807)
    __shared__ int part[512];        // 2 KB
    __shared__ int stage[CAP_B];     // 26 KB
    int b = blockIdx.x, t = threadIdx.x;

    int seg = 0;
    if (b >= cfg.qbase[3]) seg = 3;
    else if (b >= cfg.qbase[2]) seg = 2;
    else if (b >= cfg.qbase[1]) seg = 1;
    int lb = b - cfg.qbase[seg];
    int row0 = cfg.soff[seg] + lb * cfg.rpb[seg];
    int nr = cfg.rows[seg] - lb * cfg.rpb[seg];
    if (nr > cfg.rpb[seg]) nr = cfg.rpb[seg];
    int n = gcur[b];
    if (n > CAP_B) n = CAP_B;        // overflow guard (matches split clamp)
    const unsigned long long* src = bkt + (size_t)b * CAP_B;

    // block-uniform source table and destination base
    const float* emb = (seg == 0 || seg == 3) ? entity_emb : user_emb;
    float* dbase;
    if (seg == 0)      dbase = out     + (size_t)row0 * DD;
    else if (seg == 1) dbase = usr_out + (size_t)(row0 - cfg.soff[1]) * DD;
    else if (seg == 2) dbase = iu      + (size_t)(row0 - cfg.soff[2]) * DD;
    else               dbase = ui      + (size_t)(row0 - cfg.soff[3]) * DD;

    cnt[t] = 0; cnt[t + 512] = 0;
    __syncthreads();
    for (int i = t; i < n; i += 512) {
        int g = (int)(src[i] >> 25);
        atomicAdd(&cnt[g - row0], 1);
    }
    __syncthreads();

    // exclusive scan of cnt[0..1024): 2 elems/thread + scan of partials
    {
        int c0 = cnt[2 * t], c1 = cnt[2 * t + 1];
        int s2 = c0 + c1;
        part[t] = s2;
        __syncthreads();
        for (int off = 1; off < 512; off <<= 1) {
            int y = (t >= off) ? part[t - off] : 0;
            __syncthreads();
            part[t] += y;
            __syncthreads();
        }
        int run = part[t] - s2;
        cnt[2 * t] = run;
        cnt[2 * t + 1] = run + c0;
    }
    __syncthreads();

    // scatter payloads into LDS stage (cnt consumed as cursors -> cnt[r] = row end)
    for (int i = t; i < n; i += 512) {
        unsigned long long v = src[i];
        int lr = (int)(v >> 25) - row0;
        int pos = atomicAdd(&cnt[lr], 1);
        stage[pos] = (int)(v & 0x1FFFFFF);
    }
    __syncthreads();

    // per-row gather-reduce: wave per row, payload broadcast from LDS
    int wv = t >> 6, lane = t & 63;
    for (int r = wv; r < nr; r += 8) {
        int start = (r == 0) ? 0 : cnt[r - 1];
        int end = cnt[r];
        float acc = 0.f;
        for (int base = start; base < end; base += 64) {
            int m = end - base; if (m > 64) m = 64;
            int pv = (lane < m) ? stage[base + lane] : 0;
            int j = 0;
            for (; j + 4 <= m; j += 4) {
                int p0 = __builtin_amdgcn_readlane(pv, j);
                int p1 = __builtin_amdgcn_readlane(pv, j + 1);
                int p2 = __builtin_amdgcn_readlane(pv, j + 2);
                int p3 = __builtin_amdgcn_readlane(pv, j + 3);
                const float* r0 = emb + (((unsigned)p0 & 0xFFFFFu) << 6);
                const float* r1 = emb + (((unsigned)p1 & 0xFFFFFu) << 6);
                const float* r2 = emb + (((unsigned)p2 & 0xFFFFFu) << 6);
                const float* r3 = emb + (((unsigned)p3 & 0xFFFFFu) << 6);
                float e0 = r0[lane], w0 = weight[(((unsigned)p0 >> 20) << 6) + lane];
                float e1 = r1[lane], w1 = weight[(((unsigned)p1 >> 20) << 6) + lane];
                float e2 = r2[lane], w2 = weight[(((unsigned)p2 >> 20) << 6) + lane];
                float e3 = r3[lane], w3 = weight[(((unsigned)p3 >> 20) << 6) + lane];
                acc += e0 * w0; acc += e1 * w1; acc += e2 * w2; acc += e3 * w3;
            }
            for (; j < m; ++j) {
                int pj = __builtin_amdgcn_readlane(pv, j);
                const float* rj = emb + (((unsigned)pj & 0xFFFFFu) << 6);
                acc += rj[lane] * weight[(((unsigned)pj >> 20) << 6) + lane];
            }
        }
        int deg = end - start;
        dbase[(size_t)r * DD + lane] = acc / (float)(deg > 0 ? deg : 1);
    }
}

// ---------- gated fusion (in-place safe: per-element RAW only) ----------
__global__ void gate_fuse_kernel(const float* a_, const float* b_,
                                 const float* __restrict__ gA, const float* __restrict__ gB,
                                 float* out, int n_rows) {
    __shared__ float GA[DD][DD + 1];
    __shared__ float GB[DD][DD + 1];
    for (int i = threadIdx.x; i < DD * DD; i += blockDim.x) {
        int d = i >> 6, k = i & 63;
        GA[k][d] = gA[i];
        GB[k][d] = gB[i];
    }
    __syncthreads();
    int lane = threadIdx.x & 63;
    int waves_per_blk = blockDim.x >> 6;
    int row0 = blockIdx.x * waves_per_blk + (threadIdx.x >> 6);
    int stride = gridDim.x * waves_per_blk;
    for (int row = row0; row < n_rows; row += stride) {
        float a = a_[(size_t)row * DD + lane];
        float b = b_[(size_t)row * DD + lane];
        float z = 0.f;
#pragma unroll
        for (int k = 0; k < DD; ++k) {
            float ak = __shfl(a, k, 64);
            float bk = __shfl(b, k, 64);
            z += ak * GA[k][lane] + bk * GB[k][lane];
        }
        float g = 1.f / (1.f + expf(-z));
        out[(size_t)row * DD + lane] = g * a + (1.f - g) * b;
    }
}

extern "C" void kernel_launch(void* const* d_in, const int* in_sizes, int n_in,
                              void* d_out, int out_size, void* d_ws, size_t ws_size,
                              hipStream_t stream) {
    const float* entity_emb = (const float*)d_in[0];
    const float* user_emb   = (const float*)d_in[1];
    const float* weight     = (const float*)d_in[2];
    const float* g1         = (const float*)d_in[3];
    const float* g2         = (const float*)d_in[4];
    const float* g3         = (const float*)d_in[5];
    const int* edge_index  = (const int*)d_in[6];
    const int* edge_type   = (const int*)d_in[7];
    const int* uedge_index = (const int*)d_in[8];
    const int* uedge_type  = (const int*)d_in[9];
    const int* mat_row     = (const int*)d_in[10];
    const int* mat_col     = (const int*)d_in[11];

    const int n_entities   = in_sizes[0] / DD;  // 180000
    const int n_user_nodes = in_sizes[1] / DD;  // 150000
    const int nA           = in_sizes[7];       // 1500000
    const int nB           = in_sizes[9];       // 1000000
    const int nM           = in_sizes[10];      // 1500000
    const int n_items      = 50000;
    const int n_users      = 100000;

    const int offB = n_entities;                // 180000
    const int offC = offB + n_user_nodes;       // 330000
    const int offD = offC + n_items;            // 380000
    const int Etot = nA + nB + nM + nM;         // 5.5M

    float* out      = (float*)d_out;
    float* user_out = out + (size_t)n_entities * DD;

    // workspace (~93 MB): bkt + gcur + iu + ui
    unsigned long long* bkt = (unsigned long long*)d_ws;        // 1024*6656*8 = 54.5 MB
    int* gcur = (int*)(bkt + (size_t)NBKT * CAP_B);             // 1024
    float* iu = (float*)(gcur + NBKT);                          // 50k*64 f32
    float* ui = iu + (size_t)n_items * DD;                      // 100k*64 f32

    // expectation-balanced bucket layout
    SegCfg cfg;
    {
        int nb[4];
        nb[0] = (int)((long long)nA * NBKT / Etot);
        nb[1] = (int)((long long)nB * NBKT / Etot);
        nb[2] = (int)((long long)nM * NBKT / Etot);
        nb[3] = NBKT - nb[0] - nb[1] - nb[2];
        int rows[4] = {n_entities, n_user_nodes, n_items, n_users};
        int soff[4] = {0, offB, offC, offD};
        int qb = 0;
        for (int s = 0; s < 4; ++s) {
            cfg.qbase[s] = qb;
            cfg.rpb[s]   = (rows[s] + nb[s] - 1) / nb[s];
            cfg.inv[s]   = 1.0f / (float)cfg.rpb[s];
            cfg.soff[s]  = soff[s];
            cfg.rows[s]  = rows[s];
            qb += nb[s];
        }
    }

    hipMemsetAsync(gcur, 0, NBKT * sizeof(int), stream);

    int nchunk = (Etot + CHUNK - 1) / CHUNK;    // 672
    split_kernel<<<nchunk, 512, 0, stream>>>(edge_index, edge_index + nA, edge_type,
                                             uedge_index, uedge_index + nB, uedge_type,
                                             mat_col, mat_row,
                                             mat_row, mat_col,
                                             nA, nB, nM, nM, cfg, gcur, bkt);
    sort_gather<<<NBKT, 512, 0, stream>>>(bkt, gcur, cfg,
                                          entity_emb, user_emb, weight,
                                          out, user_out, iu, ui);

    gate_fuse_kernel<<<1024, 256, 0, stream>>>(out, iu, g1, g2, out, n_items);
    gate_fuse_kernel<<<2048, 256, 0, stream>>>(user_out, ui, g3, g2, user_out, n_users);
}

// Round 8
// 564.469 us; speedup vs baseline: 1.3409x; 1.1836x over previous
//
#include <hip/hip_runtime.h>

#define DD 64
#define NBKT 1024
#define CHUNK 8192
#define CAP_B 6656    // bucket capacity in edges (mean 5371, ~17 sigma slack)

struct SegCfg {
    int qbase[4];   // first bucket id of segment
    int rpb[4];     // rows per bucket
    float inv[4];   // 1.f / rpb
    int soff[4];    // global row offset of segment
    int rows[4];    // rows in segment
};

// ---------- K1: 1024-way multisplit with dense, full-lane streamout ----------
__global__ void __launch_bounds__(512, 2)
split_kernel(const int* __restrict__ dA, const int* __restrict__ sA, const int* __restrict__ tA,
             const int* __restrict__ dB, const int* __restrict__ sB, const int* __restrict__ tB,
             const int* __restrict__ dC, const int* __restrict__ sC,
             const int* __restrict__ dD, const int* __restrict__ sD,
             int nA, int nB, int nC, int nD,
             SegCfg cfg, int* __restrict__ gcur, unsigned long long* __restrict__ bkt) {
    __shared__ unsigned long long ord[CHUNK];   // 64 KB
    __shared__ int cnt[NBKT];                   // 4 KB
    __shared__ int sc[NBKT];                    // 4 KB
    __shared__ int gb[NBKT];                    // 4 KB (scan scratch, then bases)
    int t = threadIdx.x;
    int Etot = nA + nB + nC + nD;
    int base = blockIdx.x * CHUNK;
    if (base >= Etot) return;

    cnt[t] = 0; cnt[t + 512] = 0;
    __syncthreads();

    unsigned long long val[16];
    int qv[16], rv[16];
#pragma unroll
    for (int k = 0; k < 16; ++k) {
        int i = base + k * 512 + t;
        qv[k] = -1;
        if (i < Etot) {
            int j = i, d, seg, pv;
            if (j < nA)              { seg = 0; d = dA[j]; pv = sA[j] | (tA[j] << 20); }
            else if ((j -= nA) < nB) { seg = 1; d = dB[j]; pv = sB[j] | (tB[j] << 20); }
            else if ((j -= nB) < nC) { seg = 2; d = dC[j]; pv = sC[j]; }
            else { j -= nC;            seg = 3; d = dD[j]; pv = sD[j]; }
            int rpb = cfg.rpb[seg];
            int q = (int)((float)d * cfg.inv[seg]);
            if (d >= (q + 1) * rpb) ++q;
            else if (d < q * rpb) --q;
            int g = d + cfg.soff[seg];
            q += cfg.qbase[seg];
            val[k] = ((unsigned long long)q << 44) | ((unsigned long long)g << 25) | (unsigned)pv;
            qv[k] = q;
            rv[k] = atomicAdd(&cnt[q], 1);
        }
    }
    __syncthreads();

    // exclusive scan of cnt[0..1024): 2 elems/thread, gb[] as partial scratch
    int c0 = cnt[2 * t], c1 = cnt[2 * t + 1];
    {
        int s2 = c0 + c1;
        gb[t] = s2;
        __syncthreads();
        for (int off = 1; off < 512; off <<= 1) {
            int x = (t >= off) ? gb[t - off] : 0;
            __syncthreads();
            gb[t] += x;
            __syncthreads();
        }
        int run = gb[t] - s2;
        sc[2 * t] = run;
        sc[2 * t + 1] = run + c0;
    }
    __syncthreads();
    // per-bucket global bases (overwrite gb)
    gb[2 * t]     = c0 ? atomicAdd(&gcur[2 * t], c0) : 0;
    gb[2 * t + 1] = c1 ? atomicAdd(&gcur[2 * t + 1], c1) : 0;
    __syncthreads();

#pragma unroll
    for (int k = 0; k < 16; ++k)
        if (qv[k] >= 0) ord[sc[qv[k]] + rv[k]] = val[k];
    __syncthreads();

    // full-lane dense streamout (capacity-clamped: overflow drops, never faults)
    int tot = sc[NBKT - 1] + cnt[NBKT - 1];
    for (int i = t; i < tot; i += 512) {
        unsigned long long v = ord[i];
        int q = (int)(v >> 44);
        int idx = gb[q] + (i - sc[q]);
        if (idx < CAP_B)
            bkt[(size_t)q * CAP_B + idx] = v & 0xFFFFFFFFFFFULL;
    }
}

// ---------- K2: fused per-bucket counting sort + gather-reduce ----------
__global__ void __launch_bounds__(512, 2)
sort_gather(const unsigned long long* __restrict__ bkt, const int* __restrict__ gcur,
            SegCfg cfg,
            const float* __restrict__ entity_emb, const float* __restrict__ user_emb,
            const float* __restrict__ weight,
            float* __restrict__ out, float* __restrict__ usr_out,
            float* __restrict__ iu, float* __restrict__ ui) {
    __shared__ int cnt[1024];        // 4 KB (rows/bucket <= 807)
    __shared__ int part[512];        // 2 KB
    __shared__ int stage[CAP_B];     // 26 KB
    int b = blockIdx.x, t = threadIdx.x;

    int seg = 0;
    if (b >= cfg.qbase[3]) seg = 3;
    else if (b >= cfg.qbase[2]) seg = 2;
    else if (b >= cfg.qbase[1]) seg = 1;
    int lb = b - cfg.qbase[seg];
    int row0 = cfg.soff[seg] + lb * cfg.rpb[seg];
    int nr = cfg.rows[seg] - lb * cfg.rpb[seg];
    if (nr > cfg.rpb[seg]) nr = cfg.rpb[seg];
    int n = gcur[b];
    if (n > CAP_B) n = CAP_B;        // overflow guard (matches split clamp)
    const unsigned long long* src = bkt + (size_t)b * CAP_B;

    // block-uniform source table and destination base
    const float* emb = (seg == 0 || seg == 3) ? entity_emb : user_emb;
    float* dbase;
    if (seg == 0)      dbase = out     + (size_t)row0 * DD;
    else if (seg == 1) dbase = usr_out + (size_t)(row0 - cfg.soff[1]) * DD;
    else if (seg == 2) dbase = iu      + (size_t)(row0 - cfg.soff[2]) * DD;
    else               dbase = ui      + (size_t)(row0 - cfg.soff[3]) * DD;

    cnt[t] = 0; cnt[t + 512] = 0;
    __syncthreads();
    for (int i = t; i < n; i += 512) {
        int g = (int)(src[i] >> 25);
        atomicAdd(&cnt[g - row0], 1);
    }
    __syncthreads();

    // exclusive scan of cnt[0..1024): 2 elems/thread + scan of partials
    {
        int c0 = cnt[2 * t], c1 = cnt[2 * t + 1];
        int s2 = c0 + c1;
        part[t] = s2;
        __syncthreads();
        for (int off = 1; off < 512; off <<= 1) {
            int y = (t >= off) ? part[t - off] : 0;
            __syncthreads();
            part[t] += y;
            __syncthreads();
        }
        int run = part[t] - s2;
        cnt[2 * t] = run;
        cnt[2 * t + 1] = run + c0;
    }
    __syncthreads();

    // scatter payloads into LDS stage (cnt consumed as cursors -> cnt[r] = row end)
    for (int i = t; i < n; i += 512) {
        unsigned long long v = src[i];
        int lr = (int)(v >> 25) - row0;
        int pos = atomicAdd(&cnt[lr], 1);
        stage[pos] = (int)(v & 0x1FFFFFF);
    }
    __syncthreads();

    // per-row gather-reduce: wave per row, payload broadcast from LDS
    int wv = t >> 6, lane = t & 63;
    for (int r = wv; r < nr; r += 8) {
        int start = (r == 0) ? 0 : cnt[r - 1];
        int end = cnt[r];
        float acc = 0.f;
        for (int base = start; base < end; base += 64) {
            int m = end - base; if (m > 64) m = 64;
            int pv = (lane < m) ? stage[base + lane] : 0;
            int j = 0;
            for (; j + 4 <= m; j += 4) {
                int p0 = __builtin_amdgcn_readlane(pv, j);
                int p1 = __builtin_amdgcn_readlane(pv, j + 1);
                int p2 = __builtin_amdgcn_readlane(pv, j + 2);
                int p3 = __builtin_amdgcn_readlane(pv, j + 3);
                const float* r0 = emb + (((unsigned)p0 & 0xFFFFFu) << 6);
                const float* r1 = emb + (((unsigned)p1 & 0xFFFFFu) << 6);
                const float* r2 = emb + (((unsigned)p2 & 0xFFFFFu) << 6);
                const float* r3 = emb + (((unsigned)p3 & 0xFFFFFu) << 6);
                float e0 = r0[lane], w0 = weight[(((unsigned)p0 >> 20) << 6) + lane];
                float e1 = r1[lane], w1 = weight[(((unsigned)p1 >> 20) << 6) + lane];
                float e2 = r2[lane], w2 = weight[(((unsigned)p2 >> 20) << 6) + lane];
                float e3 = r3[lane], w3 = weight[(((unsigned)p3 >> 20) << 6) + lane];
                acc += e0 * w0; acc += e1 * w1; acc += e2 * w2; acc += e3 * w3;
            }
            for (; j < m; ++j) {
                int pj = __builtin_amdgcn_readlane(pv, j);
                const float* rj = emb + (((unsigned)pj & 0xFFFFFu) << 6);
                acc += rj[lane] * weight[(((unsigned)pj >> 20) << 6) + lane];
            }
        }
        int deg = end - start;
        dbase[(size_t)r * DD + lane] = acc / (float)(deg > 0 ? deg : 1);
    }
}

// ---------- gated fusion v2: W in VGPRs, activations via scalar (SMEM) loads ----------
// Lane d holds rows d of gA/gB in 128 registers (static-indexed). row is forced
// wave-uniform (readfirstlane) so a_[row*64+k] / b_[row*64+k] are uniform
// no-clobber loads -> s_load_dwordx16 into SGPRs -> v_fma with scalar operand.
// Zero LDS ops in the hot loop (old version: 256 LDS-pipe ops/row ~ LDS-bound).
// In-place (a_ == out) is safe: each row is read-then-written by exactly one
// wave, rows are 256B-aligned (no K$ line sharing), K$ invalidated at dispatch.
__global__ void __launch_bounds__(256)
gate_fuse_kernel(const float* __restrict__ a_, const float* __restrict__ b_,
                 const float* __restrict__ gA, const float* __restrict__ gB,
                 float* __restrict__ out, int n_rows) {
    int lane = threadIdx.x & 63;
    float wa[DD], wb[DD];
    {
        const float4* ga4 = (const float4*)(gA + (lane << 6));
        const float4* gb4 = (const float4*)(gB + (lane << 6));
#pragma unroll
        for (int k4 = 0; k4 < 16; ++k4) {
            float4 va = ga4[k4];
            float4 vb = gb4[k4];
            wa[4 * k4 + 0] = va.x; wa[4 * k4 + 1] = va.y;
            wa[4 * k4 + 2] = va.z; wa[4 * k4 + 3] = va.w;
            wb[4 * k4 + 0] = vb.x; wb[4 * k4 + 1] = vb.y;
            wb[4 * k4 + 2] = vb.z; wb[4 * k4 + 3] = vb.w;
        }
    }
    int wid = blockIdx.x * (blockDim.x >> 6) + (threadIdx.x >> 6);
    int nw = gridDim.x * (blockDim.x >> 6);
    for (int row = wid; row < n_rows; row += nw) {
        int row_s = __builtin_amdgcn_readfirstlane(row);
        const float* ar = a_ + ((size_t)row_s << 6);
        const float* br = b_ + ((size_t)row_s << 6);
        float z = 0.f;
#pragma unroll
        for (int k = 0; k < DD; ++k) z = fmaf(ar[k], wa[k], z);
#pragma unroll
        for (int k = 0; k < DD; ++k) z = fmaf(br[k], wb[k], z);
        float g = 1.f / (1.f + expf(-z));
        float av = ar[lane], bv = br[lane];
        out[((size_t)row_s << 6) + lane] = g * av + (1.f - g) * bv;
    }
}

extern "C" void kernel_launch(void* const* d_in, const int* in_sizes, int n_in,
                              void* d_out, int out_size, void* d_ws, size_t ws_size,
                              hipStream_t stream) {
    const float* entity_emb = (const float*)d_in[0];
    const float* user_emb   = (const float*)d_in[1];
    const float* weight     = (const float*)d_in[2];
    const float* g1         = (const float*)d_in[3];
    const float* g2         = (const float*)d_in[4];
    const float* g3         = (const float*)d_in[5];
    const int* edge_index  = (const int*)d_in[6];
    const int* edge_type   = (const int*)d_in[7];
    const int* uedge_index = (const int*)d_in[8];
    const int* uedge_type  = (const int*)d_in[9];
    const int* mat_row     = (const int*)d_in[10];
    const int* mat_col     = (const int*)d_in[11];

    const int n_entities   = in_sizes[0] / DD;  // 180000
    const int n_user_nodes = in_sizes[1] / DD;  // 150000
    const int nA           = in_sizes[7];       // 1500000
    const int nB           = in_sizes[9];       // 1000000
    const int nM           = in_sizes[10];      // 1500000
    const int n_items      = 50000;
    const int n_users      = 100000;

    const int offB = n_entities;                // 180000
    const int offC = offB + n_user_nodes;       // 330000
    const int offD = offC + n_items;            // 380000
    const int Etot = nA + nB + nM + nM;         // 5.5M

    float* out      = (float*)d_out;
    float* user_out = out + (size_t)n_entities * DD;

    // workspace (~93 MB): bkt + gcur + iu + ui
    unsigned long long* bkt = (unsigned long long*)d_ws;        // 1024*6656*8 = 54.5 MB
    int* gcur = (int*)(bkt + (size_t)NBKT * CAP_B);             // 1024
    float* iu = (float*)(gcur + NBKT);                          // 50k*64 f32
    float* ui = iu + (size_t)n_items * DD;                      // 100k*64 f32

    // expectation-balanced bucket layout
    SegCfg cfg;
    {
        int nb[4];
        nb[0] = (int)((long long)nA * NBKT / Etot);
        nb[1] = (int)((long long)nB * NBKT / Etot);
        nb[2] = (int)((long long)nM * NBKT / Etot);
        nb[3] = NBKT - nb[0] - nb[1] - nb[2];
        int rows[4] = {n_entities, n_user_nodes, n_items, n_users};
        int soff[4] = {0, offB, offC, offD};
        int qb = 0;
        for (int s = 0; s < 4; ++s) {
            cfg.qbase[s] = qb;
            cfg.rpb[s]   = (rows[s] + nb[s] - 1) / nb[s];
            cfg.inv[s]   = 1.0f / (float)cfg.rpb[s];
            cfg.soff[s]  = soff[s];
            cfg.rows[s]  = rows[s];
            qb += nb[s];
        }
    }

    hipMemsetAsync(gcur, 0, NBKT * sizeof(int), stream);

    int nchunk = (Etot + CHUNK - 1) / CHUNK;    // 672
    split_kernel<<<nchunk, 512, 0, stream>>>(edge_index, edge_index + nA, edge_type,
                                             uedge_index, uedge_index + nB, uedge_type,
                                             mat_col, mat_row,
                                             mat_row, mat_col,
                                             nA, nB, nM, nM, cfg, gcur, bkt);
    sort_gather<<<NBKT, 512, 0, stream>>>(bkt, gcur, cfg,
                                          entity_emb, user_emb, weight,
                                          out, user_out, iu, ui);

    // items: gi = sig(kg@g1.T + iu@g2.T); out = gi*kg + (1-gi)*iu   (in-place kg)
    gate_fuse_kernel<<<1024, 256, 0, stream>>>(out, iu, g1, g2, out, n_items);
    // users: hi = sig(ukg@g3.T + ui@g2.T); out = hi*ukg + (1-hi)*ui (in-place ukg)
    gate_fuse_kernel<<<1024, 256, 0, stream>>>(user_out, ui, g3, g2, user_out, n_users);
}